// Round 24
// baseline (40.008 us; speedup 1.0000x reference)
//
#include <hip/hip_runtime.h>

#define NB   4
#define CIN  32
#define HH   56
#define WW   56
#define GOUT 8
#define LOUT 8
#define KK   9
#define HW   (HH * WW)        // 3136
#define PIXTOT (NB * HW)      // 12544
#define PPB  32               // pixels per block (512 thr = 32 px * 16 lanes)
#define WSLICE 2304           // GOUT-slice floats per c (8*9*4*8)
#define WS_S 148              // per-(g,mh) LDS stride (144+4): 16B-aligned b128 slots
#define HP   58               // padded spatial dims
#define WP   58
#define THREADS 512

typedef float v4f __attribute__((ext_vector_type(4)));

static __device__ __forceinline__ v4f fma4(v4f a, v4f b, v4f c) {
    return __builtin_elementwise_fma(a, b, c);
}

// ---- pre-pass: x[n][ch][h][w] -> xt[n][hp][wp][ch] with zero border ----
__global__ __launch_bounds__(256) void transpose_x_kernel(
    const float* __restrict__ x, float* __restrict__ xt)
{
    __shared__ float tile[CIN * 57];     // 57 stride: conflict-free transposed read
    const int b = blockIdx.x;            // n*HP + hp
    const int n = b / HP;
    const int hp = b - n * HP;
    const int h = hp - 1;
    const int tid = threadIdx.x;
    const bool rowok = (unsigned)h < (unsigned)HH;

    if (rowok) {
        for (int i = tid; i < CIN * WW; i += 256) {
            const int ch = i / WW;
            const int w  = i - ch * WW;  // lanes: w consecutive -> coalesced read
            tile[ch * 57 + w] = x[((n * CIN + ch) * HH + h) * WW + w];
        }
    }
    __syncthreads();
    float* dst = xt + ((size_t)(n * HP + hp) * WP) * CIN;
    for (int i = tid; i < WP * CIN; i += 256) {
        const int wp = i >> 5;
        const int ch = i & 31;           // lanes: ch consecutive -> coalesced write
        const bool ok = rowok && (wp >= 1) && (wp <= WW);
        dst[i] = ok ? tile[ch * 57 + (wp - 1)] : 0.0f;
    }
}

// 16 lanes per pixel: lane = pl*16 + g*2 + mh. Each lane owns m-half mh
// (m = mh*4 + mi): pr shrinks to 9x4 floats -> all state fits arch VGPRs
// (no AGPR read/write tax), weight LDS reads halve.
__global__ __launch_bounds__(THREADS, 2) void caps_routing_kernel(
    const float* __restrict__ xt, const float* __restrict__ wt,
    float* __restrict__ out)
{
    // ws[(g*2+mh)][k*16 + l*4 + mi], stride 148 floats (592B: 16B-aligned)
    __shared__ __align__(16) float ws[16 * WS_S];   // 9472 B

    const int tid = threadIdx.x;
    const int c = blockIdx.y;

    const int q   = tid & 15;            // lane-in-pixel
    const int g   = q >> 1;              // input capsule group 0..7
    const int mh  = q & 1;               // m-half 0..1
    const int pl  = tid >> 4;            // 0..31
    const int pix = blockIdx.x * PPB + pl;   // 392*32 == 12544 exactly
    const int n = pix / HW;
    const int p = pix - n * HW;
    const int h = p / WW;
    const int w = p - h * WW;

    // ---- x-gather: 9 unconditional float4 loads (padded layout) ----
    v4f xv4[KK];
    const float* base = xt + ((size_t)((n * HP + h) * WP + w)) * CIN + g * 4;
    #pragma unroll
    for (int ki = 0; ki < 3; ++ki)
        #pragma unroll
        for (int kj = 0; kj < 3; ++kj)
            xv4[ki * 3 + kj] =
                *reinterpret_cast<const v4f*>(base + (ki * WP + kj) * CIN);

    // ---- stage weights: dest r = k*16 + l*4 + mi for (g,mh) ----
    {
        const float* wc = wt + c * WSLICE;
        for (int i = tid; i < 2304; i += THREADS) {
            const int g2 = i / 144;
            const int r  = i - g2 * 144;
            const int k  = r >> 4;
            const int l  = (r >> 2) & 3;
            const int mi = r & 3;
            ws[g2 * WS_S + r] =
                wc[(g2 >> 1) * 288 + k * 32 + l * 8 + (g2 & 1) * 4 + mi];
        }
    }
    __syncthreads();

    // ---- priors: pr4[k] = own 4 m-components; 4 b128 + 16 FMA per k ----
    v4f pr4[KK];
    v4f ks4 = {0.f, 0.f, 0.f, 0.f};
    const float* wg = &ws[q * WS_S];
    #pragma unroll
    for (int k = 0; k < KK; ++k) {
        const v4f* w4 = reinterpret_cast<const v4f*>(wg + k * 16);
        const v4f wl0 = w4[0], wl1 = w4[1], wl2 = w4[2], wl3 = w4[3];
        v4f a = v4f{xv4[k][0], xv4[k][0], xv4[k][0], xv4[k][0]} * wl0;
        a = fma4(v4f{xv4[k][1], xv4[k][1], xv4[k][1], xv4[k][1]}, wl1, a);
        a = fma4(v4f{xv4[k][2], xv4[k][2], xv4[k][2], xv4[k][2]}, wl2, a);
        a = fma4(v4f{xv4[k][3], xv4[k][3], xv4[k][3], xv4[k][3]}, wl3, a);
        pr4[k] = a;
        ks4 += a;
    }

    // ---- dynamic routing, ITERS = 3 ----
    float logits[KK];
    #pragma unroll
    for (int k = 0; k < KK; ++k) logits[k] = 0.0f;

    v4f vv4;
    #pragma unroll
    for (int it = 0; it < 3; ++it) {
        v4f s4;
        float pre;
        if (it == 0) {
            s4 = ks4;
            pre = 1.0f / 9.0f;
        } else {
            float e[KK];
            float sum = 0.0f;
            #pragma unroll
            for (int k = 0; k < KK; ++k) { e[k] = __expf(logits[k]); sum += e[k]; }
            const float inv = __builtin_amdgcn_rcpf(sum);
            s4 = v4f{0.f, 0.f, 0.f, 0.f};
            #pragma unroll
            for (int k = 0; k < KK; ++k)
                s4 = fma4(v4f{e[k], e[k], e[k], e[k]}, pr4[k], s4);
            const v4f inv4 = {inv, inv, inv, inv};
            s4 *= inv4;
            pre = 1.0f;
        }

        // reduce over the 8 g's: xor lane bits 1,2,3 (mh bit 0 untouched)
        #pragma unroll
        for (int off = 2; off <= 8; off <<= 1) {
            #pragma unroll
            for (int j = 0; j < 4; ++j)
                s4[j] += __shfl_xor(s4[j], off, 64);
        }

        // squash: partial n2 over own half, one xor-1 exchange for the full n2
        float n2p = s4[0] * s4[0];
        n2p = fmaf(s4[1], s4[1], n2p);
        n2p = fmaf(s4[2], s4[2], n2p);
        n2p = fmaf(s4[3], s4[3], n2p);
        const float n2full = n2p + __shfl_xor(n2p, 1, 64);
        const float n2 = n2full * (pre * pre);
        const float f = n2 * __builtin_amdgcn_rsqf(fmaxf(n2, 1e-30f))
                           * __builtin_amdgcn_rcpf(1.0f + n2);
        const float qsc = f * pre;
        vv4 = v4f{qsc, qsc, qsc, qsc} * s4;

        if (it != 2) {
            #pragma unroll
            for (int k = 0; k < KK; ++k) {
                float d = pr4[k][0] * vv4[0];
                d = fmaf(pr4[k][1], vv4[1], d);
                d = fmaf(pr4[k][2], vv4[2], d);
                d = fmaf(pr4[k][3], vv4[3], d);
                logits[k] += d + __shfl_xor(d, 1, 64);
            }
        }
    }

    // output component m = g: held by the lane with mh == g>>2 at index g&3
    if (mh == (g >> 2)) {
        float outv = vv4[0];
        #pragma unroll
        for (int mi = 1; mi < 4; ++mi) if ((g & 3) == mi) outv = vv4[mi];
        out[(n * GOUT * LOUT + c * LOUT + g) * HW + p] = outv;
    }
}

extern "C" void kernel_launch(void* const* d_in, const int* in_sizes, int n_in,
                              void* d_out, int out_size, void* d_ws, size_t ws_size,
                              hipStream_t stream) {
    const float* x  = (const float*)d_in[0];
    const float* wt = (const float*)d_in[1];
    float* out = (float*)d_out;
    float* xt = (float*)d_ws;   // 4*58*58*32 floats = 1.72 MB scratch

    transpose_x_kernel<<<dim3(NB * HP), dim3(256), 0, stream>>>(x, xt);
    dim3 grid(PIXTOT / PPB, GOUT);   // 392 x 8, 512 threads
    caps_routing_kernel<<<grid, dim3(THREADS), 0, stream>>>(xt, wt, out);
}

// Round 28
// 31.074 us; speedup vs baseline: 1.2875x; 1.2875x over previous
//
#include <hip/hip_runtime.h>

#define NB   4
#define CIN  32
#define HH   56
#define WW   56
#define GOUT 8
#define LOUT 8
#define KK   9
#define HW   (HH * WW)        // 3136
#define WSLICE 2304           // GOUT-slice floats per c (8*9*4*8)
#define WS_G 292              // padded per-g LDS stride -> conflict-free float4 reads
#define HP   58               // padded spatial dims
#define WP   58
#define THREADS 448           // one image row: 56 px * 8 g

typedef float v2f __attribute__((ext_vector_type(2)));
typedef float v4f __attribute__((ext_vector_type(4)));

static __device__ __forceinline__ v2f fma2(v2f a, v2f b, v2f c) {
    return __builtin_elementwise_fma(a, b, c);
}

// DPP xor-add over the 8-lane g-group: quad_perm(1,0,3,2)=0xB1 (lane^1),
// quad_perm(2,3,0,1)=0x4E (lane^2), row_half_mirror=0x141 (lane^7 within 8;
// valid for step 3 because quad-sums are already quad-uniform).
#define DPP_XADD(x, CTRL) \
    (x) += __int_as_float(__builtin_amdgcn_update_dpp( \
        0, __float_as_int(x), (CTRL), 0xF, 0xF, true))

// ---- pre-pass: x[n][ch][h][w] -> xt[n][hp][wp][ch] with zero border ----
__global__ __launch_bounds__(256) void transpose_x_kernel(
    const float* __restrict__ x, float* __restrict__ xt)
{
    __shared__ float tile[CIN * 57];     // 57 stride: conflict-free transposed read
    const int b = blockIdx.x;            // n*HP + hp
    const int n = b / HP;
    const int hp = b - n * HP;
    const int h = hp - 1;
    const int tid = threadIdx.x;
    const bool rowok = (unsigned)h < (unsigned)HH;

    if (rowok) {
        for (int i = tid; i < CIN * WW; i += 256) {
            const int ch = i / WW;
            const int w  = i - ch * WW;  // lanes: w consecutive -> coalesced read
            tile[ch * 57 + w] = x[((n * CIN + ch) * HH + h) * WW + w];
        }
    }
    __syncthreads();
    float* dst = xt + ((size_t)(n * HP + hp) * WP) * CIN;
    for (int i = tid; i < WP * CIN; i += 256) {
        const int wp = i >> 5;
        const int ch = i & 31;           // lanes: ch consecutive -> coalesced write
        const bool ok = rowok && (wp >= 1) && (wp <= WW);
        dst[i] = ok ? tile[ch * 57 + (wp - 1)] : 0.0f;
    }
}

// Launch-bounds experiment: (448,4) -> <=128-reg budget (math proven to fit
// at r15's (256,4)); allows 2x resident blocks vs a >128-reg allocation.
__global__ __launch_bounds__(THREADS, 4) void caps_routing_kernel(
    const float* __restrict__ xt, const float* __restrict__ wt,
    float* __restrict__ out)
{
    __shared__ __align__(16) float ws[8 * WS_G];   // 9344 B

    const int tid = threadIdx.x;
    const int c = blockIdx.y;
    const int rr = blockIdx.x;        // n*56 + h  (block-uniform -> SALU math)
    const int n = rr / HH;
    const int h = rr - n * HH;

    const int g = tid & 7;
    const int w = tid >> 3;           // 0..55

    // ---- x-gather: 9 unconditional float4 loads (padded layout) ----
    v4f xv4[KK];
    const float* base = xt + ((size_t)((n * HP + h) * WP + w)) * CIN + g * 4;
    #pragma unroll
    for (int ki = 0; ki < 3; ++ki)
        #pragma unroll
        for (int kj = 0; kj < 3; ++kj)
            xv4[ki * 3 + kj] =
                *reinterpret_cast<const v4f*>(base + (ki * WP + kj) * CIN);

    // ---- stage this c's weight slice: [g][k][l][m], per-g padded to 292 ----
    if (tid < 256) {
        const int gg = tid >> 5;
        const int r0 = tid & 31;
        const float* src = wt + c * WSLICE + gg * 288;
        float* dst = ws + gg * WS_G;
        #pragma unroll
        for (int j = 0; j < 9; ++j)
            dst[r0 + j * 32] = src[r0 + j * 32];
    }
    __syncthreads();

    // ---- priors (packed pairs): pr2[k][j] = m-pair j of prior vector k ----
    v2f pr2[KK][4];
    v2f ks2[4] = {v2f{0.f,0.f}, v2f{0.f,0.f}, v2f{0.f,0.f}, v2f{0.f,0.f}};

    const float* wg = &ws[g * WS_G];
    #pragma unroll
    for (int k = 0; k < KK; ++k) {
        v2f a0 = {0.f,0.f}, a1 = {0.f,0.f}, a2 = {0.f,0.f}, a3 = {0.f,0.f};
        #pragma unroll
        for (int l = 0; l < 4; ++l) {
            const float xsv = xv4[k][l];
            const v2f xs2 = {xsv, xsv};
            const v4f w01 = *reinterpret_cast<const v4f*>(wg + k * 32 + l * 8);
            const v4f w23 = *reinterpret_cast<const v4f*>(wg + k * 32 + l * 8 + 4);
            a0 = fma2(xs2, __builtin_shufflevector(w01, w01, 0, 1), a0);
            a1 = fma2(xs2, __builtin_shufflevector(w01, w01, 2, 3), a1);
            a2 = fma2(xs2, __builtin_shufflevector(w23, w23, 0, 1), a2);
            a3 = fma2(xs2, __builtin_shufflevector(w23, w23, 2, 3), a3);
        }
        pr2[k][0] = a0; pr2[k][1] = a1; pr2[k][2] = a2; pr2[k][3] = a3;
        ks2[0] += a0; ks2[1] += a1; ks2[2] += a2; ks2[3] += a3;
    }

    // ---- dynamic routing, ITERS = 3 (normalized probs — bounded) ----
    float logits[KK];
    #pragma unroll
    for (int k = 0; k < KK; ++k) logits[k] = 0.0f;

    v2f vv[4];
    #pragma unroll
    for (int it = 0; it < 3; ++it) {
        v2f s2[4];
        float pre;   // scale applied to the reduced raw sum before squash
        if (it == 0) {
            #pragma unroll
            for (int j = 0; j < 4; ++j) s2[j] = ks2[j];
            pre = 1.0f / 9.0f;
        } else {
            float e[KK];
            float sum = 0.0f;
            #pragma unroll
            for (int k = 0; k < KK; ++k) { e[k] = __expf(logits[k]); sum += e[k]; }
            const float inv = __builtin_amdgcn_rcpf(sum);  // sum in [~1e-12, 3e4]: safe
            #pragma unroll
            for (int j = 0; j < 4; ++j) s2[j] = v2f{0.f, 0.f};
            #pragma unroll
            for (int k = 0; k < KK; ++k) {
                const v2f ek = {e[k], e[k]};
                #pragma unroll
                for (int j = 0; j < 4; ++j) s2[j] = fma2(ek, pr2[k][j], s2[j]);
            }
            const v2f inv2 = {inv, inv};
            #pragma unroll
            for (int j = 0; j < 4; ++j) s2[j] *= inv2;
            pre = 1.0f;
        }

        // g-group all-reduce via DPP (VALU-only, no LDS pipe)
        #pragma unroll
        for (int j = 0; j < 4; ++j) { DPP_XADD(s2[j].x, 0xB1); DPP_XADD(s2[j].y, 0xB1); }
        #pragma unroll
        for (int j = 0; j < 4; ++j) { DPP_XADD(s2[j].x, 0x4E); DPP_XADD(s2[j].y, 0x4E); }
        #pragma unroll
        for (int j = 0; j < 4; ++j) { DPP_XADD(s2[j].x, 0x141); DPP_XADD(s2[j].y, 0x141); }

        // squash on s_true = pre*s2: n2 = pre^2*|s2|^2, v = (pre*f)*s2
        v2f tq = s2[0] * s2[0];
        tq = fma2(s2[1], s2[1], tq);
        tq = fma2(s2[2], s2[2], tq);
        tq = fma2(s2[3], s2[3], tq);
        const float n2 = (tq.x + tq.y) * (pre * pre);
        const float f = n2 * __builtin_amdgcn_rsqf(fmaxf(n2, 1e-30f))
                           * __builtin_amdgcn_rcpf(1.0f + n2);
        const float q = f * pre;
        const v2f q2 = {q, q};
        #pragma unroll
        for (int j = 0; j < 4; ++j) vv[j] = q2 * s2[j];

        if (it != 2) {
            #pragma unroll
            for (int k = 0; k < KK; ++k) {
                v2f d2 = pr2[k][0] * vv[0];
                d2 = fma2(pr2[k][1], vv[1], d2);
                d2 = fma2(pr2[k][2], vv[2], d2);
                d2 = fma2(pr2[k][3], vv[3], d2);
                logits[k] += d2.x + d2.y;
            }
        }
    }

    // lane (w, g) writes output component m = g (static select chain)
    const float vs[8] = { vv[0].x, vv[0].y, vv[1].x, vv[1].y,
                          vv[2].x, vv[2].y, vv[3].x, vv[3].y };
    float outv = vs[0];
    #pragma unroll
    for (int m = 1; m < LOUT; ++m) if (g == m) outv = vs[m];
    out[(n * GOUT * LOUT + c * LOUT + g) * HW + h * WW + w] = outv;
}

extern "C" void kernel_launch(void* const* d_in, const int* in_sizes, int n_in,
                              void* d_out, int out_size, void* d_ws, size_t ws_size,
                              hipStream_t stream) {
    const float* x  = (const float*)d_in[0];
    const float* wt = (const float*)d_in[1];
    float* out = (float*)d_out;
    float* xt = (float*)d_ws;   // 4*58*58*32 floats = 1.72 MB scratch

    transpose_x_kernel<<<dim3(NB * HP), dim3(256), 0, stream>>>(x, xt);
    dim3 grid(NB * HH, GOUT);   // 224 x 8, 448 threads (one row x one c)
    caps_routing_kernel<<<grid, dim3(THREADS), 0, stream>>>(xt, wt, out);
}

// Round 29
// 30.711 us; speedup vs baseline: 1.3027x; 1.0118x over previous
//
#include <hip/hip_runtime.h>

#define NB   4
#define CIN  32
#define HH   56
#define WW   56
#define GOUT 8
#define LOUT 8
#define KK   9
#define HW   (HH * WW)        // 3136
#define WSLICE 2304           // GOUT-slice floats per c (8*9*4*8)
#define WS_G 292              // padded per-g LDS stride -> conflict-free float4 reads
#define HP   58               // padded spatial dims
#define WP   58
#define THREADS 448           // one image row: 56 px * 8 g

typedef float v2f __attribute__((ext_vector_type(2)));
typedef float v4f __attribute__((ext_vector_type(4)));

static __device__ __forceinline__ v2f fma2(v2f a, v2f b, v2f c) {
    return __builtin_elementwise_fma(a, b, c);
}

// DPP xor-add over the 8-lane g-group: quad_perm(1,0,3,2)=0xB1 (lane^1),
// quad_perm(2,3,0,1)=0x4E (lane^2), row_half_mirror=0x141 (lane^7 within 8;
// valid for step 3 because quad-sums are already quad-uniform).
#define DPP_XADD(x, CTRL) \
    (x) += __int_as_float(__builtin_amdgcn_update_dpp( \
        0, __float_as_int(x), (CTRL), 0xF, 0xF, true))

// ---- pre-pass: x[n][ch][h][w] -> xt[n][hp][wp][ch] with zero border ----
__global__ __launch_bounds__(256) void transpose_x_kernel(
    const float* __restrict__ x, float* __restrict__ xt)
{
    __shared__ float tile[CIN * 57];     // 57 stride: conflict-free transposed read
    const int b = blockIdx.x;            // n*HP + hp
    const int n = b / HP;
    const int hp = b - n * HP;
    const int h = hp - 1;
    const int tid = threadIdx.x;
    const bool rowok = (unsigned)h < (unsigned)HH;

    if (rowok) {
        for (int i = tid; i < CIN * WW; i += 256) {
            const int ch = i / WW;
            const int w  = i - ch * WW;  // lanes: w consecutive -> coalesced read
            tile[ch * 57 + w] = x[((n * CIN + ch) * HH + h) * WW + w];
        }
    }
    __syncthreads();
    float* dst = xt + ((size_t)(n * HP + hp) * WP) * CIN;
    for (int i = tid; i < WP * CIN; i += 256) {
        const int wp = i >> 5;
        const int ch = i & 31;           // lanes: ch consecutive -> coalesced write
        const bool ok = rowok && (wp >= 1) && (wp <= WW);
        dst[i] = ok ? tile[ch * 57 + (wp - 1)] : 0.0f;
    }
}

__global__ __launch_bounds__(THREADS, 2) void caps_routing_kernel(
    const float* __restrict__ xt, const float* __restrict__ wt,
    float* __restrict__ out)
{
    __shared__ __align__(16) float ws[8 * WS_G];   // 9344 B

    const int tid = threadIdx.x;
    const int c = blockIdx.y;
    const int rr = blockIdx.x;        // n*56 + h  (block-uniform -> SALU math)
    const int n = rr / HH;
    const int h = rr - n * HH;

    const int g = tid & 7;
    const int w = tid >> 3;           // 0..55

    // ---- x-gather: 9 unconditional float4 loads (padded layout) ----
    v4f xv4[KK];
    const float* base = xt + ((size_t)((n * HP + h) * WP + w)) * CIN + g * 4;
    #pragma unroll
    for (int ki = 0; ki < 3; ++ki)
        #pragma unroll
        for (int kj = 0; kj < 3; ++kj)
            xv4[ki * 3 + kj] =
                *reinterpret_cast<const v4f*>(base + (ki * WP + kj) * CIN);

    // ---- stage this c's weight slice: [g][k][l][m], per-g padded to 292 ----
    if (tid < 256) {
        const int gg = tid >> 5;
        const int r0 = tid & 31;
        const float* src = wt + c * WSLICE + gg * 288;
        float* dst = ws + gg * WS_G;
        #pragma unroll
        for (int j = 0; j < 9; ++j)
            dst[r0 + j * 32] = src[r0 + j * 32];
    }
    __syncthreads();

    // ---- priors (packed pairs): pr2[k][j] = m-pair j of prior vector k ----
    v2f pr2[KK][4];
    v2f ks2[4] = {v2f{0.f,0.f}, v2f{0.f,0.f}, v2f{0.f,0.f}, v2f{0.f,0.f}};

    const float* wg = &ws[g * WS_G];
    #pragma unroll
    for (int k = 0; k < KK; ++k) {
        v2f a0 = {0.f,0.f}, a1 = {0.f,0.f}, a2 = {0.f,0.f}, a3 = {0.f,0.f};
        #pragma unroll
        for (int l = 0; l < 4; ++l) {
            const float xsv = xv4[k][l];
            const v2f xs2 = {xsv, xsv};
            const v4f w01 = *reinterpret_cast<const v4f*>(wg + k * 32 + l * 8);
            const v4f w23 = *reinterpret_cast<const v4f*>(wg + k * 32 + l * 8 + 4);
            a0 = fma2(xs2, __builtin_shufflevector(w01, w01, 0, 1), a0);
            a1 = fma2(xs2, __builtin_shufflevector(w01, w01, 2, 3), a1);
            a2 = fma2(xs2, __builtin_shufflevector(w23, w23, 0, 1), a2);
            a3 = fma2(xs2, __builtin_shufflevector(w23, w23, 2, 3), a3);
        }
        pr2[k][0] = a0; pr2[k][1] = a1; pr2[k][2] = a2; pr2[k][3] = a3;
        ks2[0] += a0; ks2[1] += a1; ks2[2] += a2; ks2[3] += a3;
    }

    // ---- dynamic routing, ITERS = 3 (normalized probs — bounded) ----
    float logits[KK];
    #pragma unroll
    for (int k = 0; k < KK; ++k) logits[k] = 0.0f;

    v2f vv[4];
    #pragma unroll
    for (int it = 0; it < 3; ++it) {
        v2f s2[4];
        float pre;   // scale applied to the reduced raw sum before squash
        if (it == 0) {
            #pragma unroll
            for (int j = 0; j < 4; ++j) s2[j] = ks2[j];
            pre = 1.0f / 9.0f;
        } else {
            float e[KK];
            float sum = 0.0f;
            #pragma unroll
            for (int k = 0; k < KK; ++k) { e[k] = __expf(logits[k]); sum += e[k]; }
            const float inv = __builtin_amdgcn_rcpf(sum);  // sum in [~1e-12, 3e4]: safe
            #pragma unroll
            for (int j = 0; j < 4; ++j) s2[j] = v2f{0.f, 0.f};
            #pragma unroll
            for (int k = 0; k < KK; ++k) {
                const v2f ek = {e[k], e[k]};
                #pragma unroll
                for (int j = 0; j < 4; ++j) s2[j] = fma2(ek, pr2[k][j], s2[j]);
            }
            const v2f inv2 = {inv, inv};
            #pragma unroll
            for (int j = 0; j < 4; ++j) s2[j] *= inv2;
            pre = 1.0f;
        }

        // g-group all-reduce via DPP (VALU-only, no LDS pipe)
        #pragma unroll
        for (int j = 0; j < 4; ++j) { DPP_XADD(s2[j].x, 0xB1); DPP_XADD(s2[j].y, 0xB1); }
        #pragma unroll
        for (int j = 0; j < 4; ++j) { DPP_XADD(s2[j].x, 0x4E); DPP_XADD(s2[j].y, 0x4E); }
        #pragma unroll
        for (int j = 0; j < 4; ++j) { DPP_XADD(s2[j].x, 0x141); DPP_XADD(s2[j].y, 0x141); }

        // squash on s_true = pre*s2: n2 = pre^2*|s2|^2, v = (pre*f)*s2
        v2f tq = s2[0] * s2[0];
        tq = fma2(s2[1], s2[1], tq);
        tq = fma2(s2[2], s2[2], tq);
        tq = fma2(s2[3], s2[3], tq);
        const float n2 = (tq.x + tq.y) * (pre * pre);
        const float f = n2 * __builtin_amdgcn_rsqf(fmaxf(n2, 1e-30f))
                           * __builtin_amdgcn_rcpf(1.0f + n2);
        const float q = f * pre;
        const v2f q2 = {q, q};
        #pragma unroll
        for (int j = 0; j < 4; ++j) vv[j] = q2 * s2[j];

        if (it != 2) {
            #pragma unroll
            for (int k = 0; k < KK; ++k) {
                v2f d2 = pr2[k][0] * vv[0];
                d2 = fma2(pr2[k][1], vv[1], d2);
                d2 = fma2(pr2[k][2], vv[2], d2);
                d2 = fma2(pr2[k][3], vv[3], d2);
                logits[k] += d2.x + d2.y;
            }
        }
    }

    // lane (w, g) writes output component m = g (static select chain)
    const float vs[8] = { vv[0].x, vv[0].y, vv[1].x, vv[1].y,
                          vv[2].x, vv[2].y, vv[3].x, vv[3].y };
    float outv = vs[0];
    #pragma unroll
    for (int m = 1; m < LOUT; ++m) if (g == m) outv = vs[m];
    out[(n * GOUT * LOUT + c * LOUT + g) * HW + h * WW + w] = outv;
}

extern "C" void kernel_launch(void* const* d_in, const int* in_sizes, int n_in,
                              void* d_out, int out_size, void* d_ws, size_t ws_size,
                              hipStream_t stream) {
    const float* x  = (const float*)d_in[0];
    const float* wt = (const float*)d_in[1];
    float* out = (float*)d_out;
    float* xt = (float*)d_ws;   // 4*58*58*32 floats = 1.72 MB scratch

    transpose_x_kernel<<<dim3(NB * HP), dim3(256), 0, stream>>>(x, xt);
    dim3 grid(NB * HH, GOUT);   // 224 x 8, 448 threads (one row x one c)
    caps_routing_kernel<<<grid, dim3(THREADS), 0, stream>>>(xt, wt, out);
}